// Round 1
// 193.300 us; speedup vs baseline: 1.0192x; 1.0192x over previous
//
#include <hip/hip_runtime.h>
#include <hip/hip_bf16.h>
#include <math.h>

#define NN 325
#define FD 64
#define KH 4
#define DH 16
#define BT 192
#define NN2 (NN*NN)
#define PST (NN*DH)     // 5200 elems per (proj,head,bt) slice
#define VTS  352        // vT row stride (bf16)
#define VSLICE (16*VTS) // vT per-(h,bt) slice
#define HSTR 72         // ffn LDS stride (bf16)
#define PLW 352         // attn P LDS row stride (bf16)
#define NPROJ 975
#define NBIAS 1848                       // 4*336*352 / 256 exactly
#define NPAD  (KH*BT)                    // 768
#define LOG2E 1.44269504088896f

typedef __attribute__((ext_vector_type(8))) short short8;
typedef __attribute__((ext_vector_type(4))) float f32x4;

union U8 { uint4 u; short8 s; ushort us[8]; };
__device__ inline short8 lds8(const ushort* p){ U8 t; t.u = *(const uint4*)p; return t.s; }
__device__ inline float b2f(ushort v){ return __uint_as_float(((unsigned)v) << 16); }
__device__ inline ushort f2b(float f){
  unsigned u = __float_as_uint(f);
  u += 0x7fff + ((u >> 16) & 1);
  return (ushort)(u >> 16);
}
__device__ inline unsigned pk2(float a, float b){
  union { __hip_bfloat162 h; unsigned u; } t;
  t.h = __float22bfloat162_rn(float2{a, b});
  return t.u;
}
__device__ inline short8 cvt8(const float* p){
  float4 u = ((const float4*)p)[0], v = ((const float4*)p)[1];
  U8 t;
  t.us[0]=f2b(u.x); t.us[1]=f2b(u.y); t.us[2]=f2b(u.z); t.us[3]=f2b(u.w);
  t.us[4]=f2b(v.x); t.us[5]=f2b(v.y); t.us[6]=f2b(v.z); t.us[7]=f2b(v.w);
  return t.s;
}

// ---------------- wpack: W's -> Wcat bf16 [448][64] + bcat + identity frags ----------------
__global__ __launch_bounds__(256) void wpack_kernel(
    const float* __restrict__ Wq,  const float* __restrict__ bq,
    const float* __restrict__ Wk,  const float* __restrict__ bk,
    const float* __restrict__ Wks, const float* __restrict__ bks,
    const float* __restrict__ Wv,  const float* __restrict__ bv,
    const float* __restrict__ Wvs, const float* __restrict__ bvs,
    const float* __restrict__ Wf1, const float* __restrict__ Wf2,
    ushort* __restrict__ Wcat, float* __restrict__ bcat,
    ushort* __restrict__ idT){
  int blk = blockIdx.x;
  if (blk == 7){
    // identity A-fragment table, replicated 21x for uniform ct stride:
    // idT[ct][l32][j] = (l32&15) == ((l32>>4)*8 + j) ? bf16(1.0) : 0
    for (int e = threadIdx.x; e < 672; e += 256){
      int l = e & 31, mm = l & 15, gg = l >> 4;
      U8 t;
      #pragma unroll
      for (int j = 0; j < 8; ++j) t.us[j] = (mm == gg*8 + j) ? (ushort)0x3F80 : (ushort)0;
      *(uint4*)(idT + (size_t)e*8) = t.u;
    }
    return;
  }
  const float* Ws[7] = {Wq, Wk, Wks, Wv, Wvs, Wf1, Wf2};
  const float* bs[5] = {bq, bk, bks, bv, bvs};
  int f = blk * 64 + (threadIdx.x >> 2);
  int c0 = (threadIdx.x & 3) * 8;
  const float* wr = Ws[blk] + (f & 63) * 64;
  unsigned* dst = (unsigned*)Wcat + f * 32 + c0;
  #pragma unroll
  for (int c = 0; c < 8; ++c)
    dst[c] = f2b(wr[2*(c0+c)]) | ((unsigned)f2b(wr[2*(c0+c)+1]) << 16);
  if (blk < 5 && (threadIdx.x & 3) == 0) bcat[f] = bs[blk][f & 63];
}

// ---------------- prep: proj (+V->vt direct) | bias bf16 [4][336][352] | vt pad zero ----------------
__global__ __launch_bounds__(256) void prep_kernel(
    const float* __restrict__ x, const ushort* __restrict__ Wcat,
    const float* __restrict__ bcat, ushort* __restrict__ proj,
    ushort* __restrict__ vt,
    const float* __restrict__ Wdi, const float* __restrict__ Wdo,
    const float* __restrict__ A,   const float* __restrict__ AT,
    ushort* __restrict__ biasB){
  int bid = blockIdx.x, tid = threadIdx.x;
  if (bid < NPROJ){
    // ---- projections via MFMA (A=W rows, B=x rows) ----
    int lane = tid & 63, wid = tid >> 6;
    int r0 = bid * 64 + wid * 16;
    int m = lane & 15, g = lane >> 4;
    int gr = r0 + m;
    int bt = gr / NN, n = gr - bt * NN;
    const float* xr = x + (size_t)gr * 64 + g * 8;
    short8 xb0 = cvt8(xr);
    short8 xb1 = cvt8(xr + 32);
    for (int ct = 0; ct < 20; ++ct){
      short8 w0 = lds8(Wcat + ((size_t)(ct*16 + m) * 64 + g * 8));
      short8 w1 = lds8(Wcat + ((size_t)(ct*16 + m) * 64 + g * 8 + 32));
      float4 b4 = *(const float4*)(bcat + ct*16 + 4*g);
      f32x4 acc = {b4.x, b4.y, b4.z, b4.w};
      acc = __builtin_amdgcn_mfma_f32_16x16x32_bf16(w0, xb0, acc, 0, 0, 0);
      acc = __builtin_amdgcn_mfma_f32_16x16x32_bf16(w1, xb1, acc, 0, 0, 0);
      if (ct >= 12 && ct < 16){
        // V head (ct-12): write transposed directly to vt[d][n]
        ushort* vs = vt + (size_t)((ct-12)*BT + bt) * VSLICE + n;
        #pragma unroll
        for (int rg = 0; rg < 4; ++rg)
          vs[(size_t)(4*g + rg) * VTS] = f2b(acc[rg]);
      } else {
        // fold 1/sqrt(D) AND log2(e) into Q (softmax runs on exp2)
        float sc = (ct < 4) ? 0.25f * LOG2E : 1.0f;
        uint2 w;
        w.x = pk2(acc[0]*sc, acc[1]*sc);
        w.y = pk2(acc[2]*sc, acc[3]*sc);
        *(uint2*)(proj + ((size_t)ct * BT + bt) * PST + n*16 + 4*g) = w;
      }
    }
  } else if (bid < NPROJ + NBIAS){
    // ---- bias bf16 [4][336][352], x log2e; pads = -1e30 (exp2 -> 0 mask) ----
    int idx = (bid - NPROJ) * 256 + tid;
    int h = idx / 118272;                 // 336*352
    int rem = idx - h * 118272;
    int n = rem / 352, mc = rem - n * 352;
    float s = -1e30f;
    if (n < NN && mc < NN){
      int r = n * NN + mc;
      s = 0.f;
      if (h < 2){
        #pragma unroll
        for (int k = 0; k < 3; ++k) s += Wdi[(h*3 + k)*NN2 + r] * A[k*NN2 + r];
      } else {
        int h2 = h - 2;
        #pragma unroll
        for (int k = 0; k < 3; ++k) s += Wdo[(h2*3 + k)*NN2 + r] * AT[k*NN2 + r];
      }
      s *= LOG2E;
    }
    biasB[idx] = f2b(s);
  } else {
    // ---- vt pad: zero cols 325..351 for one (h,bt) slice ----
    int slice = bid - NPROJ - NBIAS;
    ushort* vs = vt + (size_t)slice * VSLICE;
    if (tid < 432){
      int d = tid / 27, c = NN + tid % 27;
      vs[(size_t)d * VTS + c] = 0;
    }
  }
}

// ---------------- attention: ONE WAVE per (h,bt,qt) tile, zero block barriers ----------------
// QK^T computed swapped (mfma(K,Q)) so each lane's 4 acc values share one q-row;
// bias folded into the same MFMA via k=16..31 (A-high = one-hot identity, B-high = bias frag).
// Softmax fully in-register; LDS used only for the P C-layout -> A-fragment transpose
// (per-wave slice, wave-local s_waitcnt lgkmcnt(0) sync — same pattern as ffn_kernel).
__global__ __launch_bounds__(256, 3) void attn_kernel(
    const ushort* __restrict__ proj, const ushort* __restrict__ biasB,
    const ushort* __restrict__ idT, const ushort* __restrict__ vt,
    ushort* __restrict__ val){
  __shared__ __align__(16) ushort Pl[4][16*PLW];
  int tid = threadIdx.x, lane = tid & 63, wid = tid >> 6;
  int tile = blockIdx.x * 4 + wid;          // 4032*4 = 16128 = 4*192*21 tiles
  int qt = tile % 21, bh = tile / 21;
  int h = bh / BT, bt = bh - h * BT;
  int m = lane & 15, g = lane >> 4;

  const ushort* qb  = proj + (size_t)((0*KH + h)*BT + bt) * PST;
  const ushort* kb  = proj + (size_t)((1*KH + h)*BT + bt) * PST;
  const ushort* ksb = proj + (size_t)((2*KH + h)*BT + bt) * PST;
  const ushort* vsb = proj + (size_t)((4*KH + h)*BT + bt) * PST;

  // A operand: g<2 -> K rows (tokens ct*16+m, k=g*8..), g>=2 -> identity frags (uniform ct stride 256)
  const ushort* pa0 = (g < 2) ? (kb + m*16 + g*8) : (idT + (size_t)(lane & 31)*8);
  // B operand: g<2 -> Q row qt*16+m (ct-invariant, L1 hit), g>=2 -> bias frag (ct stride 16)
  const ushort* pb0 = (g < 2)
      ? (qb + (size_t)(qt*16 + m)*16 + g*8)
      : (biasB + (size_t)(h*336 + qt*16 + m)*352 + (g-2)*8);
  int bstep = (g < 2) ? 0 : 16;

  // -------- fused QK^T + bias + exp2 + pack-to-LDS --------
  ushort* Pw = &Pl[wid][m*PLW + g*4];
  float rowsum = 0.f;
  #pragma unroll
  for (int ct = 0; ct < 21; ++ct){
    short8 a = lds8(pa0 + ct*256);
    short8 b = lds8(pb0 + ct*bstep);
    f32x4 acc = {0.f, 0.f, 0.f, 0.f};
    acc = __builtin_amdgcn_mfma_f32_16x16x32_bf16(a, b, acc, 0, 0, 0);
    // acc[rg] = S'[tok=ct*16+g*4+rg][q=m] incl. bias, already in log2 domain
    float e0 = __builtin_amdgcn_exp2f(acc[0]);
    float e1 = __builtin_amdgcn_exp2f(acc[1]);
    float e2 = __builtin_amdgcn_exp2f(acc[2]);
    float e3 = __builtin_amdgcn_exp2f(acc[3]);
    rowsum += (e0 + e1) + (e2 + e3);
    uint2 w; w.x = pk2(e0, e1); w.y = pk2(e2, e3);
    *(uint2*)(Pw + ct*16) = w;               // P[q=m][ct*16+g*4 .. +3]
  }
  { uint2 z; z.x = 0u; z.y = 0u; *(uint2*)(Pw + 336) = z; }  // tokens 336..351 = 0

  // full row-m sum (lanes differ only in token subset across g)
  rowsum += __shfl_xor(rowsum, 16, 64);
  rowsum += __shfl_xor(rowsum, 32, 64);

  // sigmoid gate: dp = (q * 0.25*log2e) . ks over 16 dims (4 dims per g-lane)
  int nq = qt*16 + m, nb = min(nq, NN-1);
  uint2 qw = *(const uint2*)(qb + (size_t)nb*16 + g*4);
  uint2 kw = *(const uint2*)(ksb + (size_t)nb*16 + g*4);
  float dp = b2f((ushort)(qw.x & 0xffff)) * b2f((ushort)(kw.x & 0xffff))
           + b2f((ushort)(qw.x >> 16))    * b2f((ushort)(kw.x >> 16))
           + b2f((ushort)(qw.y & 0xffff)) * b2f((ushort)(kw.y & 0xffff))
           + b2f((ushort)(qw.y >> 16))    * b2f((ushort)(kw.y >> 16));
  dp += __shfl_xor(dp, 16, 64);
  dp += __shfl_xor(dp, 32, 64);
  float esv  = __builtin_amdgcn_rcpf(1.f + __builtin_amdgcn_exp2f(-dp));
  float inv  = __builtin_amdgcn_rcpf(esv + rowsum);
  float beta = 1.f - rowsum * inv;

  // wave-local LDS sync (cross-lane write->read within the wave; ffn-proven pattern)
  asm volatile("s_waitcnt lgkmcnt(0)" ::: "memory");

  // -------- PV: A = P rows from LDS, B = vT rows from global (imm-offset walk) --------
  const ushort* Pr  = &Pl[wid][m*PLW + g*8];
  const ushort* vtg = vt + (size_t)(h*BT + bt)*VSLICE + (size_t)m*VTS + g*8;
  f32x4 o = {0.f, 0.f, 0.f, 0.f};
  #pragma unroll
  for (int tt = 0; tt < 11; ++tt){
    short8 pf = lds8(Pr + tt*32);
    short8 vf = lds8(vtg + tt*32);
    o = __builtin_amdgcn_mfma_f32_16x16x32_bf16(pf, vf, o, 0, 0, 0);
  }

  // redistribute row stats: lane (m,g) needs rows 4g+rg (held by lanes 0..15)
  int sb = g << 4;
  float invr[4], betr[4];
  #pragma unroll
  for (int rg = 0; rg < 4; ++rg){
    invr[rg] = __uint_as_float(__builtin_amdgcn_ds_bpermute(sb + rg*4, __float_as_uint(inv)));
    betr[rg] = __uint_as_float(__builtin_amdgcn_ds_bpermute(sb + rg*4, __float_as_uint(beta)));
  }
  #pragma unroll
  for (int rg = 0; rg < 4; ++rg){
    int n = qt*16 + 4*g + rg;
    int nc = min(n, NN-1);
    float vsx = b2f(vsb[(size_t)nc*16 + m]);
    float res = o[rg]*invr[rg] + betr[rg]*vsx;
    if (n < NN) val[((size_t)bt*NN + n)*FD + h*16 + m] = f2b(res);
  }
}

// ---------------- FFN + residual + LayerNorm (swapped operands, no barrier) ----------------
__global__ __launch_bounds__(256) void ffn_kernel(
    const ushort* __restrict__ val, const float* __restrict__ x,
    const ushort* __restrict__ Wf1b, const float* __restrict__ bf1,
    const ushort* __restrict__ Wf2b, const float* __restrict__ bf2,
    const float* __restrict__ g_ln, const float* __restrict__ b_ln,
    float* __restrict__ out){
  __shared__ ushort hs[4][16 * HSTR];   // wave-private slices
  int tid = threadIdx.x, lane = tid & 63, wid = tid >> 6;
  int m = lane & 15, g = lane >> 4;
  int r0 = blockIdx.x * 64 + wid * 16;
  int row = r0 + m;

  short8 vb0 = lds8(val + ((size_t)row * 64 + g * 8));
  short8 vb1 = lds8(val + ((size_t)row * 64 + g * 8 + 32));

  #pragma unroll
  for (int ct = 0; ct < 4; ++ct){
    short8 w0 = lds8(Wf1b + ((size_t)(ct*16 + m) * 64 + g * 8));
    short8 w1 = lds8(Wf1b + ((size_t)(ct*16 + m) * 64 + g * 8 + 32));
    float4 b4 = *(const float4*)(bf1 + ct*16 + 4*g);
    f32x4 acc = {b4.x, b4.y, b4.z, b4.w};
    acc = __builtin_amdgcn_mfma_f32_16x16x32_bf16(w0, vb0, acc, 0, 0, 0);
    acc = __builtin_amdgcn_mfma_f32_16x16x32_bf16(w1, vb1, acc, 0, 0, 0);
    uint2 w;
    float g0 = 0.5f*acc[0]*(1.f + erff(acc[0]*0.70710678118654752f));
    float g1 = 0.5f*acc[1]*(1.f + erff(acc[1]*0.70710678118654752f));
    float g2 = 0.5f*acc[2]*(1.f + erff(acc[2]*0.70710678118654752f));
    float g3 = 0.5f*acc[3]*(1.f + erff(acc[3]*0.70710678118654752f));
    w.x = pk2(g0, g1); w.y = pk2(g2, g3);
    *(uint2*)&hs[wid][m * HSTR + ct*16 + 4*g] = w;
  }
  asm volatile("s_waitcnt lgkmcnt(0)" ::: "memory");
  short8 h0 = lds8(&hs[wid][m * HSTR + g * 8]);
  short8 h1 = lds8(&hs[wid][m * HSTR + g * 8 + 32]);

  float t[4][4];
  #pragma unroll
  for (int ct = 0; ct < 4; ++ct){
    short8 w0 = lds8(Wf2b + ((size_t)(ct*16 + m) * 64 + g * 8));
    short8 w1 = lds8(Wf2b + ((size_t)(ct*16 + m) * 64 + g * 8 + 32));
    float4 b4 = *(const float4*)(bf2 + ct*16 + 4*g);
    f32x4 acc = {b4.x, b4.y, b4.z, b4.w};
    acc = __builtin_amdgcn_mfma_f32_16x16x32_bf16(w0, h0, acc, 0, 0, 0);
    acc = __builtin_amdgcn_mfma_f32_16x16x32_bf16(w1, h1, acc, 0, 0, 0);
    float4 xr = *(const float4*)(x + (size_t)row * 64 + ct*16 + 4*g);
    t[ct][0] = acc[0] + xr.x; t[ct][1] = acc[1] + xr.y;
    t[ct][2] = acc[2] + xr.z; t[ct][3] = acc[3] + xr.w;
  }
  float s = 0.f;
  #pragma unroll
  for (int ct = 0; ct < 4; ++ct) s += (t[ct][0]+t[ct][1]) + (t[ct][2]+t[ct][3]);
  s += __shfl_xor(s, 16, 64); s += __shfl_xor(s, 32, 64);
  float mu = s * (1.f/64.f);
  float v = 0.f;
  #pragma unroll
  for (int ct = 0; ct < 4; ++ct){
    #pragma unroll
    for (int rg = 0; rg < 4; ++rg){ float d = t[ct][rg] - mu; v += d*d; }
  }
  v += __shfl_xor(v, 16, 64); v += __shfl_xor(v, 32, 64);
  float rs = rsqrtf(v * (1.f/64.f) + 1e-5f);
  #pragma unroll
  for (int ct = 0; ct < 4; ++ct){
    float4 g4 = *(const float4*)(g_ln + ct*16 + 4*g);
    float4 bb = *(const float4*)(b_ln + ct*16 + 4*g);
    float4 o;
    o.x = g4.x*(t[ct][0]-mu)*rs + bb.x;
    o.y = g4.y*(t[ct][1]-mu)*rs + bb.y;
    o.z = g4.z*(t[ct][2]-mu)*rs + bb.z;
    o.w = g4.w*(t[ct][3]-mu)*rs + bb.w;
    *(float4*)(out + (size_t)row * 64 + ct*16 + 4*g) = o;
  }
}

extern "C" void kernel_launch(void* const* d_in, const int* in_sizes, int n_in,
                              void* d_out, int out_size, void* d_ws, size_t ws_size,
                              hipStream_t stream) {
  const float* x    = (const float*)d_in[0];
  const float* A    = (const float*)d_in[1];
  const float* AT   = (const float*)d_in[2];
  const float* Wq   = (const float*)d_in[3];
  const float* bq   = (const float*)d_in[4];
  const float* Wk   = (const float*)d_in[5];
  const float* bk   = (const float*)d_in[6];
  const float* Wks  = (const float*)d_in[7];
  const float* bks  = (const float*)d_in[8];
  const float* Wv   = (const float*)d_in[9];
  const float* bv   = (const float*)d_in[10];
  const float* Wvs  = (const float*)d_in[11];
  const float* bvs  = (const float*)d_in[12];
  const float* Wdi  = (const float*)d_in[13];
  const float* Wdo  = (const float*)d_in[14];
  const float* Wf1  = (const float*)d_in[15];
  const float* bf1  = (const float*)d_in[16];
  const float* Wf2  = (const float*)d_in[17];
  const float* bf2  = (const float*)d_in[18];
  const float* g_ln = (const float*)d_in[19];
  const float* b_ln = (const float*)d_in[20];
  float* out = (float*)d_out;

  float* ws = (float*)d_ws;
  ushort* proj  = (ushort*)ws;                     // bf16, 19,968,000 el (p=3 unused)
  ushort* biasB = (ushort*)(ws + 9984000);         // bf16, 473,088 el [4][336][352]
  ushort* idT   = biasB + 473088;                  // bf16, 5,376 el [21][32][8]
  ushort* val   = (ushort*)(ws + 10441600);        // bf16, 3,993,600 el
  ushort* vt    = (ushort*)(ws + 12438400);        // bf16, 4,325,376 el
  ushort* Wcat  = (ushort*)(ws + 14601088);        // bf16, 28,672 el
  float*  bcat  = ws + 14615424;                   // fp32, 320
  ushort* Wf1b  = Wcat + 320*64;
  ushort* Wf2b  = Wcat + 384*64;

  wpack_kernel<<<8, 256, 0, stream>>>(Wq, bq, Wk, bk, Wks, bks,
                                      Wv, bv, Wvs, bvs, Wf1, Wf2, Wcat, bcat, idT);
  prep_kernel<<<NPROJ + NBIAS + NPAD, 256, 0, stream>>>(
      x, Wcat, bcat, proj, vt, Wdi, Wdo, A, AT, biasB);
  attn_kernel<<<4032, 256, 0, stream>>>(proj, biasB, idT, vt, val);
  ffn_kernel<<<975, 256, 0, stream>>>(val, x, Wf1b, bf1, Wf2b, bf2,
                                      g_ln, b_ln, out);
}